// Round 4
// baseline (324.768 us; speedup 1.0000x reference)
//
#include <hip/hip_runtime.h>
#include <float.h>
#include <math.h>

#define TOKENS 16384
#define HIDDEN 2048
#define NEXP 128
#define TOPK 8
#define NCAND 12      // refine candidate count
#define NSEL 13       // select sorted-list length
#define DELTA 1e-3f

#define BM 32
#define BK 32
#define KITERS (HIDDEN / BK)   // 64

typedef float f32x4 __attribute__((ext_vector_type(4)));
typedef short bf16x8 __attribute__((ext_vector_type(8)));

__device__ __forceinline__ unsigned pack_hi(float a, float b) {
    return (__float_as_uint(a) >> 16) | (__float_as_uint(b) & 0xFFFF0000u);
}
__device__ __forceinline__ float resid(float a) {
    return a - __uint_as_float(__float_as_uint(a) & 0xFFFF0000u);
}
__device__ __forceinline__ unsigned short hi16(float a) {
    return (unsigned short)(__float_as_uint(a) >> 16);
}

// async global->LDS, 16B per lane. LDS dest = wave-uniform base + lane*16.
__device__ __forceinline__ void load_lds_16B(const void* g, void* l) {
    __builtin_amdgcn_global_load_lds(
        (const __attribute__((address_space(1))) unsigned int*)g,
        (__attribute__((address_space(3))) unsigned int*)l, 16, 0, 0);
}

// ---------------------------------------------------------------------------
// K0: pre-split W (fp32 [128][2048]) into fragment-ordered bf16 hi/lo.
// Chunk c (65536 total, 16B each): kt=c>>10, reg=(c>>6)&15 (nt*2+hl), lane=c&63.
// Chunk holds expert e = nt*16+(lane&15), k = kt*32+(lane>>4)*8 .. +7.
// ---------------------------------------------------------------------------
__global__ __launch_bounds__(256) void presplit_w(const float* __restrict__ W,
                                                  unsigned short* __restrict__ Ws) {
    const int c = blockIdx.x * 256 + threadIdx.x;
    const int lane = c & 63;
    const int reg = (c >> 6) & 15;
    const int kt = c >> 10;
    const int nt = reg >> 1, hl = reg & 1;
    const int e = nt * 16 + (lane & 15);
    const int k0 = kt * 32 + (lane >> 4) * 8;
    const float* wp = W + (size_t)e * HIDDEN + k0;
    float4 a = *(const float4*)wp;
    float4 b = *(const float4*)(wp + 4);
    if (hl) {
        a.x = resid(a.x); a.y = resid(a.y); a.z = resid(a.z); a.w = resid(a.w);
        b.x = resid(b.x); b.y = resid(b.y); b.z = resid(b.z); b.w = resid(b.w);
    }
    uint4 o;
    o.x = pack_hi(a.x, a.y); o.y = pack_hi(a.z, a.w);
    o.z = pack_hi(b.x, b.y); o.w = pack_hi(b.z, b.w);
    *(uint4*)(Ws + (size_t)c * 8) = o;
}

// ---------------------------------------------------------------------------
// K1: split-bf16 MFMA GEMM, BM=32 x BN=128(all experts) x BK=32, dbuf LDS,
// one barrier/iter, B via global_load_lds from pre-split Ws (zero VALU).
// 512 blocks x 256 thr (4 waves: wm=wid&1 tokens, wn=wid>>1 expert half).
// Wave tile 16 tok x 64 exp; 12 MFMA/iter (hh, hl, lh terms).
// A staging sigma-swizzle: chunk (g,r) at slot g*16+(r^g) -> write banks
// decorrelate; reader lane l uses same sigma. 40KB LDS -> 2 blocks/CU.
// ---------------------------------------------------------------------------
__global__ __launch_bounds__(256) void router_gemm(const float* __restrict__ X,
                                                   const unsigned short* __restrict__ Ws,
                                                   float* __restrict__ logits) {
    __shared__ unsigned short sA[2][2 * 2 * 512];   // [buf][(mt*2+hl)*512 + slot*8 + j]
    __shared__ unsigned short sB[2][16 * 512];      // [buf][(nt*2+hl)*512 + lane*8 + j]
    const int tid = threadIdx.x;
    const int lane = tid & 63;
    const int wid = tid >> 6;
    const int wm = wid & 1, wn = wid >> 1;
    const int t0 = blockIdx.x * BM;

    // A staging map: thread = (row=tid>>3, q=tid&7), covers k = q*4..q*4+3
    const int arow = tid >> 3, aq = tid & 7;
    const int ag = aq >> 1, ar = arow & 15, am = arow >> 4;
    const int aoff = (ag * 16 + (ar ^ ag)) * 8 + (aq & 1) * 4;
    const int aH = (am * 2 + 0) * 512 + aoff;
    const int aL = (am * 2 + 1) * 512 + aoff;
    const float* Xp = X + (size_t)(t0 + arow) * HIDDEN + aq * 4;

    // A fragment read offset (sigma-swizzled)
    const int rg = lane >> 4, rr = lane & 15;
    const int aRd = (rg * 16 + (rr ^ rg)) * 8;

    f32x4 acc[4];
#pragma unroll
    for (int nt = 0; nt < 4; ++nt) acc[nt] = (f32x4){0.f, 0.f, 0.f, 0.f};

    // prologue: DMA B(0), stage A(0), prefetch X(1)
    {
        const unsigned short* src = Ws + wid * 512 + lane * 8;
        unsigned short* dst = &sB[0][wid * 512];
        load_lds_16B(src, dst);
        load_lds_16B(src + 2048, dst + 2048);
        load_lds_16B(src + 4096, dst + 4096);
        load_lds_16B(src + 6144, dst + 6144);
        const float4 v = *(const float4*)(Xp);
        ushort4 h, l;
        h.x = hi16(v.x); h.y = hi16(v.y); h.z = hi16(v.z); h.w = hi16(v.w);
        l.x = hi16(resid(v.x)); l.y = hi16(resid(v.y));
        l.z = hi16(resid(v.z)); l.w = hi16(resid(v.w));
        *(ushort4*)&sA[0][aH] = h;
        *(ushort4*)&sA[0][aL] = l;
    }
    float4 xv = *(const float4*)(Xp + 32);   // X(kt=1)
    __syncthreads();   // drains DMA(0) (vmcnt0) + A writes (lgkm)

#pragma unroll 1
    for (int kt = 0; kt < KITERS; ++kt) {
        const int b = kt & 1;
        if (kt + 1 < KITERS) {
            // DMA B(kt+1) into other buffer — lands during compute below
            const unsigned short* src = Ws + (size_t)(kt + 1) * 8192 + wid * 512 + lane * 8;
            unsigned short* dst = &sB[b ^ 1][wid * 512];
            load_lds_16B(src, dst);
            load_lds_16B(src + 2048, dst + 2048);
            load_lds_16B(src + 4096, dst + 4096);
            load_lds_16B(src + 6144, dst + 6144);
            // stage A(kt+1) from prefetched regs
            ushort4 h, l;
            h.x = hi16(xv.x); h.y = hi16(xv.y); h.z = hi16(xv.z); h.w = hi16(xv.w);
            l.x = hi16(resid(xv.x)); l.y = hi16(resid(xv.y));
            l.z = hi16(resid(xv.z)); l.w = hi16(resid(xv.w));
            *(ushort4*)&sA[b ^ 1][aH] = h;
            *(ushort4*)&sA[b ^ 1][aL] = l;
        }
        if (kt + 2 < KITERS) xv = *(const float4*)(Xp + (kt + 2) * 32);

        // compute iter kt on buffer b
        const bf16x8 ah = *(const bf16x8*)&sA[b][(wm * 2 + 0) * 512 + aRd];
        const bf16x8 al = *(const bf16x8*)&sA[b][(wm * 2 + 1) * 512 + aRd];
#pragma unroll
        for (int nt = 0; nt < 4; ++nt) {
            const int rb = ((wn * 4 + nt) * 2) * 512 + lane * 8;
            const bf16x8 bh = *(const bf16x8*)&sB[b][rb];
            const bf16x8 bl = *(const bf16x8*)&sB[b][rb + 512];
            acc[nt] = __builtin_amdgcn_mfma_f32_16x16x32_bf16(ah, bh, acc[nt], 0, 0, 0);
            acc[nt] = __builtin_amdgcn_mfma_f32_16x16x32_bf16(ah, bl, acc[nt], 0, 0, 0);
            acc[nt] = __builtin_amdgcn_mfma_f32_16x16x32_bf16(al, bh, acc[nt], 0, 0, 0);
        }
        __syncthreads();   // compute(kt) done everywhere; DMA(kt+1)+A(kt+1) landed
    }

    // C/D: col(expert)=lane&15, row(token)=(lane>>4)*4+r
    const int tr = t0 + wm * 16 + (lane >> 4) * 4;
    const int ec0 = lane & 15;
#pragma unroll
    for (int nt = 0; nt < 4; ++nt) {
        const int e = (wn * 4 + nt) * 16 + ec0;
#pragma unroll
        for (int r = 0; r < 4; ++r)
            logits[(size_t)(tr + r) * NEXP + e] = acc[nt][r];
    }
}

// ---------------------------------------------------------------------------
// K2: select — scalar scan, 1 token/thread. 64-thread blocks, 64 tokens/block
// staged in LDS (stride 133 -> scan is 2-way/conflict-free). Register
// insertion-sort top-13 (static indexing only). Clean tokens write outputs;
// ambiguous (any adjacent gap among ranks 0..8 < DELTA) go to refine list.
// ---------------------------------------------------------------------------
__global__ __launch_bounds__(64) void router_select(const float* __restrict__ logits,
                                                    float* __restrict__ top_vals,
                                                    float* __restrict__ top_idx,
                                                    int* __restrict__ cnt,
                                                    int* __restrict__ list) {
    __shared__ float Ls[64 * 133];
    const int tid = threadIdx.x;
    const int t0 = blockIdx.x * 64;
#pragma unroll
    for (int i = 0; i < 32; ++i) {
        const int idx = i * 64 + tid;
        const int row = idx >> 5, c4 = (idx & 31) * 4;
        const float4 v = *(const float4*)(logits + (size_t)(t0 + row) * NEXP + c4);
        float* d = &Ls[row * 133 + c4];
        d[0] = v.x; d[1] = v.y; d[2] = v.z; d[3] = v.w;
    }
    __syncthreads();

    const float* Lr = &Ls[tid * 133];
    float vals[NSEL]; int idxs[NSEL];
#pragma unroll
    for (int j = 0; j < NSEL; ++j) { vals[j] = -FLT_MAX; idxs[j] = 0; }
    for (int e = 0; e < NEXP; ++e) {
        const float v = Lr[e];
        if (v > vals[NSEL - 1]) {
            int r = 0;
#pragma unroll
            for (int j = 0; j < NSEL; ++j) r += (vals[j] >= v) ? 1 : 0;  // ties: earlier (lower) index stays ahead
#pragma unroll
            for (int j = NSEL - 1; j > 0; --j) {
                const bool c = (j > r);
                vals[j] = c ? vals[j - 1] : vals[j];
                idxs[j] = c ? idxs[j - 1] : idxs[j];
            }
#pragma unroll
            for (int j = 0; j < NSEL; ++j) {
                const bool c = (j == r);
                vals[j] = c ? v : vals[j];
                idxs[j] = c ? e : idxs[j];
            }
        }
    }

    const int t = t0 + tid;
    float ming = FLT_MAX;
#pragma unroll
    for (int i = 0; i < TOPK; ++i) ming = fminf(ming, vals[i] - vals[i + 1]);
    if (ming < DELTA) {
        const int p = atomicAdd(cnt, 1);
        list[p] = t;
    } else {
        const float m = vals[0];
        float ex[TOPK], s = 0.f;
#pragma unroll
        for (int i = 0; i < TOPK; ++i) { ex[i] = expf(vals[i] - m); s += ex[i]; }
        const float inv = 1.f / s;
#pragma unroll
        for (int i = 0; i < TOPK; ++i) {
            top_vals[(size_t)t * TOPK + i] = ex[i] * inv;
            top_idx[(size_t)t * TOPK + i] = (float)idxs[i];
        }
    }
}

// ---------------------------------------------------------------------------
// K3: exact fp64 refine of flagged tokens (unchanged from passing round 3).
// ---------------------------------------------------------------------------
__device__ __forceinline__ void top_cand(const float* __restrict__ lrow, int lane,
                                         float* vals, int* idxs) {
    const float l0 = lrow[lane];
    const float l1 = lrow[lane + 64];
    bool r0 = false, r1 = false;
#pragma unroll
    for (int it = 0; it < NCAND; ++it) {
        const float c0 = r0 ? -FLT_MAX : l0;
        const float c1 = r1 ? -FLT_MAX : l1;
        float v; int id;
        if (c1 > c0) { v = c1; id = lane + 64; }
        else         { v = c0; id = lane; }
#pragma unroll
        for (int off = 1; off < 64; off <<= 1) {
            const float ov = __shfl_xor(v, off);
            const int   oi = __shfl_xor(id, off);
            if (ov > v || (ov == v && oi < id)) { v = ov; id = oi; }
        }
        vals[it] = v; idxs[it] = id;
        if (id == lane) r0 = true;
        else if (id == lane + 64) r1 = true;
    }
}

__global__ __launch_bounds__(256) void router_refine(const float* __restrict__ logits,
                                                     const float* __restrict__ X,
                                                     const float* __restrict__ W,
                                                     float* __restrict__ top_vals,
                                                     float* __restrict__ top_idx,
                                                     const int* __restrict__ cnt,
                                                     const int* __restrict__ list) {
    const int lane = threadIdx.x & 63;
    const int gw = blockIdx.x * 4 + (threadIdx.x >> 6);
    const int nwaves = gridDim.x * 4;
    const int n = *cnt;

    for (int ii = gw; ii < n; ii += nwaves) {
        const int t = list[ii];
        float vals[NCAND]; int idxs[NCAND];
        top_cand(logits + (size_t)t * NEXP, lane, vals, idxs);

        const float* xr = X + (size_t)t * HIDDEN;
        double xd[32];
#pragma unroll
        for (int j = 0; j < 8; ++j) {
            const float4 v = *(const float4*)(xr + j * 256 + lane * 4);
            xd[j * 4 + 0] = (double)v.x; xd[j * 4 + 1] = (double)v.y;
            xd[j * 4 + 2] = (double)v.z; xd[j * 4 + 3] = (double)v.w;
        }
        double acc[NCAND];
#pragma unroll
        for (int c = 0; c < NCAND; ++c) {
            const float* wr = W + (size_t)idxs[c] * HIDDEN;
            double a0 = 0.0, a1 = 0.0;
#pragma unroll
            for (int j = 0; j < 8; ++j) {
                const float4 w = *(const float4*)(wr + j * 256 + lane * 4);
                a0 = fma((double)w.x, xd[j * 4 + 0], a0);
                a1 = fma((double)w.y, xd[j * 4 + 1], a1);
                a0 = fma((double)w.z, xd[j * 4 + 2], a0);
                a1 = fma((double)w.w, xd[j * 4 + 3], a1);
            }
            acc[c] = a0 + a1;
        }
#pragma unroll
        for (int c = 0; c < NCAND; ++c)
#pragma unroll
            for (int off = 1; off < 64; off <<= 1)
                acc[c] += __shfl_xor(acc[c], off);

        int rank[NCAND];
#pragma unroll
        for (int c = 0; c < NCAND; ++c) {
            int r = 0;
#pragma unroll
            for (int m = 0; m < NCAND; ++m)
                if (acc[m] > acc[c] || (acc[m] == acc[c] && idxs[m] < idxs[c])) ++r;
            rank[c] = r;
        }
        double vmax = acc[0];
#pragma unroll
        for (int c = 0; c < NCAND; ++c) if (rank[c] == 0) vmax = acc[c];
        float e[NCAND], s = 0.f;
#pragma unroll
        for (int c = 0; c < NCAND; ++c) {
            e[c] = (rank[c] < TOPK) ? expf((float)(acc[c] - vmax)) : 0.f;
            s += e[c];
        }
        const float inv = 1.f / s;
        if (lane == 0) {
#pragma unroll
            for (int c = 0; c < NCAND; ++c)
                if (rank[c] < TOPK) {
                    top_vals[(size_t)t * TOPK + rank[c]] = e[c] * inv;
                    top_idx[(size_t)t * TOPK + rank[c]] = (float)idxs[c];
                }
        }
    }
}

extern "C" void kernel_launch(void* const* d_in, const int* in_sizes, int n_in,
                              void* d_out, int out_size, void* d_ws, size_t ws_size,
                              hipStream_t stream) {
    const float* X = (const float*)d_in[0];   // [16384, 2048] f32
    const float* W = (const float*)d_in[1];   // [128, 2048] f32
    float* logits = (float*)d_out;                          // [16384,128]
    float* tvals  = logits + (size_t)TOKENS * NEXP;         // [16384,8]
    float* tidx   = tvals + (size_t)TOKENS * TOPK;          // [16384,8]

    int* cnt = (int*)d_ws;
    unsigned short* Wsplit = (unsigned short*)((char*)d_ws + 4096);      // 1 MB
    int* list = (int*)((char*)d_ws + 4096 + 2 * 1024 * 1024);            // up to 64 KB

    hipMemsetAsync(d_ws, 0, 64, stream);
    presplit_w<<<256, 256, 0, stream>>>(W, Wsplit);
    router_gemm<<<TOKENS / BM, 256, 0, stream>>>(X, Wsplit, logits);
    router_select<<<TOKENS / 64, 64, 0, stream>>>(logits, tvals, tidx, cnt, list);
    router_refine<<<256, 256, 0, stream>>>(logits, X, W, tvals, tidx, cnt, list);
}